// Round 5
// baseline (18827.602 us; speedup 1.0000x reference)
//
#include <hip/hip_runtime.h>
#include <hip/hip_fp16.h>

// Persistent 2D-LSTM, all-relaxed flag protocol.
// B=64, NC=512, T=1024, F=192, K=1216 (x 0..191 | h(t-32) 192..703 | h(t-1) 704..1215).
// 2 batch groups x 128 channel-WGs = 256 WGs x 512 thr (1/CU).
// WG (g,w): batches g*32..g*32+31, channels w*4..w*4+3 (all 4 gates = 16 gate-cols).
// Weights fp16 in LDS. h ring: fp16 [slot 64][b 64][ch 512], u64 = 4 ch.
// Publish: atomic u64 ring stores -> s_waitcnt(0) -> barrier -> relaxed flag=t+1.
// Consume: poll 128 group flags >= t (relaxed, all waves) -> acquire fence -> read.

typedef __attribute__((ext_vector_type(8))) _Float16 half8;
typedef __attribute__((ext_vector_type(4))) float f32x4;
typedef unsigned long long u64;

#define T_    1024
#define FSTR  16            // flag stride in u32 (64 B)
#define OFF_RING 16384      // flags: 2*128*16*4 = 16 KB; ring: 64*64*128*8 = 4 MB

__global__ __launch_bounds__(512, 1) void lstm_persist(
    const float* __restrict__ x, const float* __restrict__ Wih,
    const float* __restrict__ Whh, const float* __restrict__ bih,
    const float* __restrict__ bhh, float* __restrict__ out,
    u64* ring, unsigned* flags)
{
    __shared__ _Float16 Wsm[38 * 64 * 8];     // 38,912 B: [chunk][lane] half8
    __shared__ float Psm[2][4][32][17];       // 17,408 B: [parity][ks][b][col]
    __shared__ float cst[128];                // c-state [b][ch_local]

    const int tid = threadIdx.x;
    const int l   = tid & 63, wv = tid >> 6;
    const int ks  = wv & 3;                   // K-split group
    const int mh  = wv >> 2;                  // batch half within group (16 rows)
    const int l15 = l & 15, l4 = l >> 4;
    const int bid = blockIdx.x;
    const int g   = bid >> 7;                 // batch group 0..1
    const int w   = bid & 127;                // channel WG 0..127

    // ---- weights -> LDS (once). col(0..15): gate=col&3, ch=w*4+(col>>2) ----
    for (int c = wv; c < 38; c += 8) {
        const int rj = (l15 & 3) * 512 + w * 4 + (l15 >> 2);
        const float* src = (c < 22)
            ? (Wih + (size_t)rj * 704 + c * 32 + l4 * 8)
            : (Whh + (size_t)rj * 512 + (c - 22) * 32 + l4 * 8);
        float4 v0 = ((const float4*)src)[0];
        float4 v1 = ((const float4*)src)[1];
        half8 hb;
        hb[0] = (_Float16)v0.x; hb[1] = (_Float16)v0.y;
        hb[2] = (_Float16)v0.z; hb[3] = (_Float16)v0.w;
        hb[4] = (_Float16)v1.x; hb[5] = (_Float16)v1.y;
        hb[6] = (_Float16)v1.z; hb[7] = (_Float16)v1.w;
        *(half8*)(Wsm + (size_t)(c * 64 + l) * 8) = hb;
    }
    if (tid < 128) cst[tid] = 0.f;

    // pointwise role (tid<128): b = tid>>2 (0..31), pc = tid&3 (ch local)
    const int pb = tid >> 2, pc = tid & 3;
    const int gc = w * 4 + pc;
    const float bI = bih[gc]        + bhh[gc];
    const float bF = bih[512 + gc]  + bhh[512 + gc];
    const float bG = bih[1024 + gc] + bhh[1024 + gc];
    const float bO = bih[1536 + gc] + bhh[1536 + gc];
    __syncthreads();

    const int gb  = g * 32 + mh * 16 + l15;   // global batch row for MFMA A
    const int nxc = (ks < 2) ? 2 : 1;         // x chunks this wave: {ks, ks+4}

    // ---- register prefetch state ----
    float4 xa[2][2];
    half8  h32[4];

    // prologue prefetch for t=0 (x only)
    {
        for (int j = 0; j < nxc; ++j) {
            const int k0 = (ks + 4 * j) * 32 + l4 * 8;
            const float* xs = x + ((size_t)(gb * 3 + (k0 >> 6)) * 256
                                   + 0 * 8 + ((k0 >> 3) & 7)) * 256 + 0 * 8;
            xa[j][0] = ((const float4*)xs)[0];
            xa[j][1] = ((const float4*)xs)[1];
        }
    }

    for (int t = 0; t < T_; ++t) {
        f32x4 acc = {0.f, 0.f, 0.f, 0.f};

        // ---- pass 1a: x (prefetched regs) ----
        for (int j = 0; j < nxc; ++j) {
            const int c = ks + 4 * j;
            half8 a;
            a[0] = (_Float16)xa[j][0].x; a[1] = (_Float16)xa[j][0].y;
            a[2] = (_Float16)xa[j][0].z; a[3] = (_Float16)xa[j][0].w;
            a[4] = (_Float16)xa[j][1].x; a[5] = (_Float16)xa[j][1].y;
            a[6] = (_Float16)xa[j][1].z; a[7] = (_Float16)xa[j][1].w;
            const half8 bf = *(const half8*)(Wsm + (size_t)(c * 64 + l) * 8);
            acc = __builtin_amdgcn_mfma_f32_16x16x32_f16(a, bf, acc, 0, 0, 0);
        }
        // ---- pass 1b: h(t-32) (prefetched regs) ----
        if (t >= 32) {
#pragma unroll
            for (int j = 0; j < 4; ++j) {
                const int c = 6 + ks + 4 * j;
                const half8 bf = *(const half8*)(Wsm + (size_t)(c * 64 + l) * 8);
                acc = __builtin_amdgcn_mfma_f32_16x16x32_f16(h32[j], bf, acc, 0, 0, 0);
            }
        }

        // ---- poll group flags >= t (all waves, relaxed) ----
        if (t > 0) {
            const unsigned* f0p = flags + ((size_t)g * 128 + l) * FSTR;
            const unsigned* f1p = flags + ((size_t)g * 128 + 64 + l) * FSTR;
            int ok;
            do {
                unsigned f0 = __hip_atomic_load(f0p, __ATOMIC_RELAXED, __HIP_MEMORY_SCOPE_AGENT);
                unsigned f1 = __hip_atomic_load(f1p, __ATOMIC_RELAXED, __HIP_MEMORY_SCOPE_AGENT);
                ok = (f0 >= (unsigned)t) && (f1 >= (unsigned)t);
            } while (!__all(ok));
            __builtin_amdgcn_fence(__ATOMIC_ACQUIRE, "agent");

            // ---- pass 2: h(t-1) ----
            const int sP = (t - 1) & 63;
            u64 v[4][2];
#pragma unroll
            for (int j = 0; j < 4; ++j) {
                const int kh = (ks + 4 * j) * 32 + l4 * 8;
                const size_t idx = ((size_t)sP * 64 + gb) * 128 + (kh >> 2);
                v[j][0] = __hip_atomic_load(ring + idx,     __ATOMIC_RELAXED, __HIP_MEMORY_SCOPE_AGENT);
                v[j][1] = __hip_atomic_load(ring + idx + 1, __ATOMIC_RELAXED, __HIP_MEMORY_SCOPE_AGENT);
            }
#pragma unroll
            for (int j = 0; j < 4; ++j) {
                union { u64 u[2]; half8 h; } cc;
                cc.u[0] = v[j][0]; cc.u[1] = v[j][1];
                const int c = 22 + ks + 4 * j;
                const half8 bf = *(const half8*)(Wsm + (size_t)(c * 64 + l) * 8);
                acc = __builtin_amdgcn_mfma_f32_16x16x32_f16(cc.h, bf, acc, 0, 0, 0);
            }
        }

        // ---- partials -> LDS (parity-buffered) ----
        const int par = t & 1;
#pragma unroll
        for (int r = 0; r < 4; ++r)
            Psm[par][ks][mh * 16 + l4 * 4 + r][l15] = acc[r];
        __syncthreads();

        // ---- pointwise + ring publish (waves 0-1) ----
        float hn = 0.f;
        if (tid < 128) {
            float gi = bI, gf = bF, gg = bG, go = bO;
#pragma unroll
            for (int k4 = 0; k4 < 4; ++k4) {
                gi += Psm[par][k4][pb][pc * 4 + 0];
                gf += Psm[par][k4][pb][pc * 4 + 1];
                gg += Psm[par][k4][pb][pc * 4 + 2];
                go += Psm[par][k4][pb][pc * 4 + 3];
            }
            const float cprev = cst[tid];
            const float si = 1.f / (1.f + __expf(-gi));
            const float sf = 1.f / (1.f + __expf(-gf));
            const float so = 1.f / (1.f + __expf(-go));
            const float tg = 2.f / (1.f + __expf(-2.f * gg)) - 1.f;
            const float cn = sf * cprev + si * tg;
            const float th = 2.f / (1.f + __expf(-2.f * cn)) - 1.f;
            hn = so * th;
            cst[tid] = cn;

            // pack 4 ch (fp16) -> one u64 per batch row, store to ring
            union { _Float16 f; unsigned short s; } cv; cv.f = (_Float16)hn;
            unsigned hb = (unsigned)cv.s;
            unsigned other = (unsigned)__shfl_xor((int)hb, 1);
            unsigned pair = (pc & 1) ? ((other & 0xffffu) | (hb << 16))
                                     : ((hb & 0xffffu) | (other << 16));
            unsigned hi = (unsigned)__shfl_xor((int)pair, 2);
            if ((tid & 3) == 0) {
                u64 val = (u64)pair | ((u64)hi << 32);
                const size_t idx = ((size_t)(t & 63) * 64 + g * 32 + pb) * 128 + w;
                __hip_atomic_store(ring + idx, val, __ATOMIC_RELAXED, __HIP_MEMORY_SCOPE_AGENT);
            }
        }
        __builtin_amdgcn_s_waitcnt(0);   // per-wave: ring stores at coherence point
        __syncthreads();
        if (tid == 0)
            __hip_atomic_store(flags + ((size_t)g * 128 + w) * FSTR, (unsigned)(t + 1),
                               __ATOMIC_RELAXED, __HIP_MEMORY_SCOPE_AGENT);
        if (tid < 128)
            out[(size_t)(g * 32 + pb) * (T_ * 512) + (size_t)t * 512 + gc] = hn;

        // ---- prefetch next step (x, h(t+1-32)) ----
        const int tn = t + 1;
        if (tn < T_) {
            const int yn = tn >> 5, xcn = tn & 31;
            for (int j = 0; j < nxc; ++j) {
                const int k0 = (ks + 4 * j) * 32 + l4 * 8;
                const float* xs = x + ((size_t)(gb * 3 + (k0 >> 6)) * 256
                                       + yn * 8 + ((k0 >> 3) & 7)) * 256 + xcn * 8;
                xa[j][0] = ((const float4*)xs)[0];
                xa[j][1] = ((const float4*)xs)[1];
            }
            if (tn >= 32) {
                const int sO = (tn - 32) & 63;
#pragma unroll
                for (int j = 0; j < 4; ++j) {
                    const int kh = (ks + 4 * j) * 32 + l4 * 8;
                    const size_t idx = ((size_t)sO * 64 + gb) * 128 + (kh >> 2);
                    u64 v0 = __hip_atomic_load(ring + idx,     __ATOMIC_RELAXED, __HIP_MEMORY_SCOPE_AGENT);
                    u64 v1 = __hip_atomic_load(ring + idx + 1, __ATOMIC_RELAXED, __HIP_MEMORY_SCOPE_AGENT);
                    union { u64 u[2]; half8 h; } cc;
                    cc.u[0] = v0; cc.u[1] = v1;
                    h32[j] = cc.h;
                }
            }
        }
    }
}

extern "C" void kernel_launch(void* const* d_in, const int* in_sizes, int n_in,
                              void* d_out, int out_size, void* d_ws, size_t ws_size,
                              hipStream_t stream) {
    const float* x   = (const float*)d_in[0];
    const float* Wih = (const float*)d_in[1];
    const float* Whh = (const float*)d_in[2];
    const float* bih = (const float*)d_in[3];
    const float* bhh = (const float*)d_in[4];
    float* out = (float*)d_out;

    char* ws = (char*)d_ws;
    unsigned* flags = (unsigned*)ws;
    u64*      ring  = (u64*)(ws + OFF_RING);

    hipMemsetAsync(flags, 0, 2 * 128 * FSTR * sizeof(unsigned), stream);
    hipLaunchKernelGGL(lstm_persist, dim3(256), dim3(512), 0, stream,
                       x, Wih, Whh, bih, bhh, out, ring, flags);
}

// Round 6
// 3195.113 us; speedup vs baseline: 5.8926x; 5.8926x over previous
//
#include <hip/hip_runtime.h>
#include <hip/hip_fp16.h>

// Persistent 2D-LSTM, self-validating tagged-ring protocol (no fences/flags).
// B=64, NC=512, T=1024, K=1216 = [x 0..191 | h(t-32) 192..703 | h(t-1) 704..1215].
// 4 batch-groups x 64 col-WGs = 256 WGs x 512 thr (1 WG/CU, 112KB LDS).
// WG (g,w): batches g*16..+15, channels w*8..+7 (x4 gates = 32 gate-cols).
// h ring: fp16 [slot 64][g 4][b 16][ch 512]; u64 = 4 ch. Each fp16's LSB is
// forced to generation parity ((t>>6)&1): consumers poll data until tags match.
// Ring pre-memset to 0x01 bytes (LSB=1) != gen-0 parity (0).

typedef __attribute__((ext_vector_type(8))) _Float16 half8;
typedef __attribute__((ext_vector_type(4))) float f32x4;
typedef unsigned long long u64;

#define T_ 1024

#define LDS_W    77824              // 38 chunks * 2 tiles * 64 lanes * 16B
#define LDS_PSM  33792              // f32 [2][8][16][33]
#define LDS_ALL  (LDS_W + LDS_PSM + 512)

extern __shared__ char smem[];

__global__ __launch_bounds__(512, 1) void lstm_persist(
    const float* __restrict__ x, const float* __restrict__ Wih,
    const float* __restrict__ Whh, const float* __restrict__ bih,
    const float* __restrict__ bhh, float* __restrict__ out,
    u64* ring)
{
    _Float16* Wsm = (_Float16*)smem;
    float*    Psm = (float*)(smem + LDS_W);
    float*    cst = (float*)(smem + LDS_W + LDS_PSM);

    const int tid = threadIdx.x;
    const int l   = tid & 63, wv = tid >> 6;
    const int l15 = l & 15,  l4 = l >> 4;
    const int bid = blockIdx.x;
    const int g   = bid >> 6;          // batch group 0..3
    const int w   = bid & 63;          // channel WG 0..63

    // ---- weights fp32 -> fp16 fragments in LDS (once) ----
    // tile col co = nb*16 + l15: gate = co&3, ch_local = co>>2 = nb*4 + (l15>>2)
    for (int p = wv; p < 76; p += 8) {
        const int c = p >> 1, nb = p & 1;
        const int rj = (l15 & 3) * 512 + w * 8 + nb * 4 + (l15 >> 2);
        const int k  = c * 32 + l4 * 8;
        const float* src = (c < 22) ? (Wih + (size_t)rj * 704 + k)
                                    : (Whh + (size_t)rj * 512 + (k - 704));
        float4 v0 = ((const float4*)src)[0];
        float4 v1 = ((const float4*)src)[1];
        half8 hb;
        hb[0]=(_Float16)v0.x; hb[1]=(_Float16)v0.y; hb[2]=(_Float16)v0.z; hb[3]=(_Float16)v0.w;
        hb[4]=(_Float16)v1.x; hb[5]=(_Float16)v1.y; hb[6]=(_Float16)v1.z; hb[7]=(_Float16)v1.w;
        *(half8*)(Wsm + (size_t)((c * 2 + nb) * 64 + l) * 8) = hb;
    }
    if (tid < 128) cst[tid] = 0.f;

    // pointwise role (tid<128): pb = batch 0..15, pc = channel 0..7
    const int pb = tid >> 3, pc = tid & 7;
    const int gc = w * 8 + pc;
    const float bI = bih[gc]        + bhh[gc];
    const float bF = bih[512 + gc]  + bhh[512 + gc];
    const float bG = bih[1024 + gc] + bhh[1024 + gc];
    const float bO = bih[1536 + gc] + bhh[1536 + gc];
    __syncthreads();

    // per-wave chunk ownership: all c in 0..37 with c%8 == wv
    const int coff = (wv + 2) & 7;
    const int c32a = 6 + coff,  c32b = 14 + coff;   // h(t-32) chunks
    const int c1a  = 22 + coff, c1b  = 30 + coff;   // h(t-1) chunks
    const int gb   = g * 16 + l15;                  // A-row batch

    auto wfrag = [&](int c, int nb) -> half8 {
        return *(const half8*)(Wsm + (size_t)((c * 2 + nb) * 64 + l) * 8);
    };
    // tagged ring fragment load: retry until all 8 fp16 LSBs == parity
    auto loadfrag = [&](int slot, int col, unsigned par_) -> half8 {
        const size_t idx = ((size_t)(slot * 4 + g) * 16 + l15) * 128 + col + l4 * 2;
        const u64 M  = 0x0001000100010001ULL;
        const u64 ex = par_ ? M : 0ULL;
        u64 v0 = 0, v1 = 0;
        bool ok = false;
        do {
            if (!ok) {
                v0 = __hip_atomic_load(ring + idx,     __ATOMIC_RELAXED, __HIP_MEMORY_SCOPE_AGENT);
                v1 = __hip_atomic_load(ring + idx + 1, __ATOMIC_RELAXED, __HIP_MEMORY_SCOPE_AGENT);
                ok = ((v0 & M) == ex) && ((v1 & M) == ex);
            }
        } while (!__all(ok));
        union { u64 u[2]; half8 h; } cc;
        cc.u[0] = v0; cc.u[1] = v1;
        return cc.h;
    };

    float4 xa0, xa1;
    half8  h32a, h32b;
    if (wv < 6) {   // x prefetch for t=0 (y=0, xc=0)
        const int k0 = wv * 32 + l4 * 8;
        const float* xs = x + ((size_t)(gb * 3 + (k0 >> 6)) * 256 + ((k0 >> 3) & 7)) * 256;
        xa0 = ((const float4*)xs)[0];
        xa1 = ((const float4*)xs)[1];
    }

    for (int t = 0; t < T_; ++t) {
        const int par = t & 1;
        f32x4 acc0 = {0.f,0.f,0.f,0.f}, acc1 = {0.f,0.f,0.f,0.f};

        // [A] x part (prefetched regs)
        if (wv < 6) {
            half8 a;
            a[0]=(_Float16)xa0.x; a[1]=(_Float16)xa0.y; a[2]=(_Float16)xa0.z; a[3]=(_Float16)xa0.w;
            a[4]=(_Float16)xa1.x; a[5]=(_Float16)xa1.y; a[6]=(_Float16)xa1.z; a[7]=(_Float16)xa1.w;
            acc0 = __builtin_amdgcn_mfma_f32_16x16x32_f16(a, wfrag(wv,0), acc0, 0,0,0);
            acc1 = __builtin_amdgcn_mfma_f32_16x16x32_f16(a, wfrag(wv,1), acc1, 0,0,0);
        }
        // [B] h(t-32) part (prefetched regs)
        if (t >= 32) {
            acc0 = __builtin_amdgcn_mfma_f32_16x16x32_f16(h32a, wfrag(c32a,0), acc0, 0,0,0);
            acc1 = __builtin_amdgcn_mfma_f32_16x16x32_f16(h32a, wfrag(c32a,1), acc1, 0,0,0);
            acc0 = __builtin_amdgcn_mfma_f32_16x16x32_f16(h32b, wfrag(c32b,0), acc0, 0,0,0);
            acc1 = __builtin_amdgcn_mfma_f32_16x16x32_f16(h32b, wfrag(c32b,1), acc1, 0,0,0);
        }
        // [C] h(t-1): tagged wait + MFMA (the only real stall)
        if (t > 0) {
            const int sP = (t - 1) & 63;
            const unsigned p1 = ((t - 1) >> 6) & 1;
            half8 ha = loadfrag(sP, (c1a - 22) * 8, p1);
            acc0 = __builtin_amdgcn_mfma_f32_16x16x32_f16(ha, wfrag(c1a,0), acc0, 0,0,0);
            acc1 = __builtin_amdgcn_mfma_f32_16x16x32_f16(ha, wfrag(c1a,1), acc1, 0,0,0);
            half8 hb = loadfrag(sP, (c1b - 22) * 8, p1);
            acc0 = __builtin_amdgcn_mfma_f32_16x16x32_f16(hb, wfrag(c1b,0), acc0, 0,0,0);
            acc1 = __builtin_amdgcn_mfma_f32_16x16x32_f16(hb, wfrag(c1b,1), acc1, 0,0,0);
        }

        // [D] partials -> LDS (parity double-buffer)
        {
            float* Pw = Psm + (size_t)((par * 8 + wv) * 16) * 33;
#pragma unroll
            for (int r = 0; r < 4; ++r) {
                Pw[(l4 * 4 + r) * 33 + l15]      = acc0[r];
                Pw[(l4 * 4 + r) * 33 + 16 + l15] = acc1[r];
            }
        }
        __syncthreads();   // [E] the only barrier per step

        // [F] pointwise + tagged publish (waves 0-1); waves 2-7 run ahead
        if (tid < 128) {
            float gi = bI, gf = bF, gg = bG, go = bO;
#pragma unroll
            for (int q = 0; q < 8; ++q) {
                const float* Pq = Psm + ((size_t)((par * 8 + q) * 16 + pb)) * 33 + pc * 4;
                gi += Pq[0]; gf += Pq[1]; gg += Pq[2]; go += Pq[3];
            }
            const float cprev = cst[tid];
            const float si = 1.f / (1.f + __expf(-gi));
            const float sf = 1.f / (1.f + __expf(-gf));
            const float so = 1.f / (1.f + __expf(-go));
            const float tg = 2.f / (1.f + __expf(-2.f * gg)) - 1.f;
            const float cn = sf * cprev + si * tg;
            const float th = 2.f / (1.f + __expf(-2.f * cn)) - 1.f;
            const float hn = so * th;
            cst[tid] = cn;

            union { _Float16 f; unsigned short s; } cv; cv.f = (_Float16)hn;
            unsigned hb16 = ((unsigned)cv.s & ~1u) | (unsigned)((t >> 6) & 1);  // force tag
            unsigned other = (unsigned)__shfl_xor((int)hb16, 1);
            unsigned pairv = (pc & 1) ? ((other & 0xffffu) | (hb16 << 16))
                                      : ((hb16 & 0xffffu) | (other << 16));
            unsigned hi = (unsigned)__shfl_xor((int)pairv, 2);
            if ((pc & 3) == 0) {
                u64 val = (u64)pairv | ((u64)hi << 32);
                const size_t idx = ((size_t)((t & 63) * 4 + g) * 16 + pb) * 128
                                 + w * 2 + (pc >> 2);
                __hip_atomic_store(ring + idx, val, __ATOMIC_RELAXED, __HIP_MEMORY_SCOPE_AGENT);
            }
            out[(size_t)(g * 16 + pb) * (T_ * 512) + (size_t)t * 512 + gc] = hn;
        }

        // [G/H] prefetch next step: x and h(t+1-32) (31-step-old => no stall)
        const int tn = t + 1;
        if (tn < T_) {
            if (wv < 6) {
                const int yn = tn >> 5, xcn = tn & 31;
                const int k0 = wv * 32 + l4 * 8;
                const float* xs = x + ((size_t)(gb * 3 + (k0 >> 6)) * 256
                                       + yn * 8 + ((k0 >> 3) & 7)) * 256 + xcn * 8;
                xa0 = ((const float4*)xs)[0];
                xa1 = ((const float4*)xs)[1];
            }
            if (tn >= 32) {
                const int sO = (tn - 32) & 63;
                const unsigned p32 = ((tn - 32) >> 6) & 1;
                h32a = loadfrag(sO, (c32a - 6) * 8, p32);
                h32b = loadfrag(sO, (c32b - 6) * 8, p32);
            }
        }
    }
}

extern "C" void kernel_launch(void* const* d_in, const int* in_sizes, int n_in,
                              void* d_out, int out_size, void* d_ws, size_t ws_size,
                              hipStream_t stream) {
    const float* x   = (const float*)d_in[0];
    const float* Wih = (const float*)d_in[1];
    const float* Whh = (const float*)d_in[2];
    const float* bih = (const float*)d_in[3];
    const float* bhh = (const float*)d_in[4];
    float* out = (float*)d_out;

    u64* ring = (u64*)d_ws;   // 64*4*16*128 u64 = 4 MB

    // LSB pattern 1 everywhere != gen-0 parity 0
    hipMemsetAsync(ring, 0x01, 64ull * 4 * 16 * 128 * 8, stream);

    static int attr_set = 0;
    (void)hipFuncSetAttribute((const void*)lstm_persist,
                              hipFuncAttributeMaxDynamicSharedMemorySize, LDS_ALL);
    (void)attr_set;

    hipLaunchKernelGGL(lstm_persist, dim3(256), dim3(512), LDS_ALL, stream,
                       x, Wih, Whh, bih, bhh, out, ring);
}